// Round 2
// baseline (416.318 us; speedup 1.0000x reference)
//
#include <hip/hip_runtime.h>
#include <hip/hip_bf16.h>
#include <math.h>

// bf16 MFMA fragment types
typedef __attribute__((ext_vector_type(8))) short bfrag;
typedef __attribute__((ext_vector_type(4))) short short4v;
typedef __attribute__((ext_vector_type(4))) float f32x4;

#define LDK 136  // padded LDS row length in bf16 elems

// NOTE: no __has_builtin guard here — it mis-fires in the hipcc HOST pass
// (amdgcn builtins unregistered for x86) and would #error a valid build.
// gfx950 has v_mfma_f32_16x16x16_bf16 (cdna4_isa.md §10); builtin:
// __builtin_amdgcn_mfma_f32_16x16x16bf16_1k(v4i16, v4i16, v4f32, ...).

// exact bf16(bits-in-short) -> f32
static __device__ __forceinline__ float b2f(short s)
{
    unsigned int u = ((unsigned int)(unsigned short)s) << 16;
    float f;
    __builtin_memcpy(&f, &u, 4);
    return f;
}

// ---------------------------------------------------------------------------
// Prep: W[128][128] fp32 -> bf16 transposed WT[n][k].
// Order in ws: 0=Wq 1=Wk 2=Wv 3=Wo 4=W1 5=W2 6=Wq_s 7=Wk_s
// ---------------------------------------------------------------------------
__global__ __launch_bounds__(256) void prep_weights(
    const float* __restrict__ Wq, const float* __restrict__ Wk,
    const float* __restrict__ Wv, const float* __restrict__ Wo,
    const float* __restrict__ W1, const float* __restrict__ W2,
    const float* __restrict__ Wqs, const float* __restrict__ Wks,
    __hip_bfloat16* __restrict__ out)
{
    __shared__ __hip_bfloat16 t[128 * 17];  // t[k][n'] for n' in slab, +1 pad
    const float* Ws[8] = {Wq, Wk, Wv, Wo, W1, W2, Wqs, Wks};
    const int mat = blockIdx.x >> 3;
    const int slab = blockIdx.x & 7;
    const float* W = Ws[mat];
    const int n0 = slab * 16;
    __hip_bfloat16* o = out + (size_t)mat * 16384 + (size_t)n0 * 128;

#pragma unroll
    for (int p = 0; p < 2; ++p) {
        int idx = p * 256 + threadIdx.x;  // 512 float4 slots = 128 rows x 4
        int k = idx >> 2, c4 = idx & 3;
        float4 f = *(const float4*)(W + k * 128 + n0 + c4 * 4);
        __hip_bfloat16* d = t + k * 17 + c4 * 4;
        d[0] = __float2bfloat16(f.x); d[1] = __float2bfloat16(f.y);
        d[2] = __float2bfloat16(f.z); d[3] = __float2bfloat16(f.w);
    }
    __syncthreads();
    {
        int n = threadIdx.x >> 4;          // 0..15 within slab
        int k0 = (threadIdx.x & 15) * 8;   // 0..120
        __hip_bfloat16 v[8];
#pragma unroll
        for (int j = 0; j < 8; ++j) v[j] = t[(k0 + j) * 17 + n];  // WT[n][k]=W[k][n]
        *(bfrag*)(o + n * 128 + k0) = *(const bfrag*)v;
    }
}

// ---------------------------------------------------------------------------
// Swapped-operand matmul: OUT[32][128] = X[32][128] @ W, with A = WT rows,
// B = X rows. Result fragment: acc[rt][c][r] = OUT[rt*16+m][(ct0+c)*16+quad*4+r]
// -> 4 CONSECUTIVE output columns per lane -> 8B vector LDS stores.
// ---------------------------------------------------------------------------
__device__ __forceinline__ void mm_accT(const __hip_bfloat16* X,
                                        const __hip_bfloat16* __restrict__ wT,
                                        int m, int quad, int ct0, f32x4 acc[2][2])
{
    const f32x4 z = {0.f, 0.f, 0.f, 0.f};
    acc[0][0] = z; acc[0][1] = z; acc[1][0] = z; acc[1][1] = z;
#pragma unroll
    for (int kk = 0; kk < 128; kk += 32) {
        const int k = kk + quad * 8;
        bfrag x0 = *(const bfrag*)(X + m * LDK + k);
        bfrag x1 = *(const bfrag*)(X + (16 + m) * LDK + k);
        bfrag w0 = *(const bfrag*)(wT + (size_t)(ct0 * 16 + m) * 128 + k);
        bfrag w1 = *(const bfrag*)(wT + (size_t)((ct0 + 1) * 16 + m) * 128 + k);
        acc[0][0] = __builtin_amdgcn_mfma_f32_16x16x32_bf16(w0, x0, acc[0][0], 0, 0, 0);
        acc[1][0] = __builtin_amdgcn_mfma_f32_16x16x32_bf16(w0, x1, acc[1][0], 0, 0, 0);
        acc[0][1] = __builtin_amdgcn_mfma_f32_16x16x32_bf16(w1, x0, acc[0][1], 0, 0, 0);
        acc[1][1] = __builtin_amdgcn_mfma_f32_16x16x32_bf16(w1, x1, acc[1][1], 0, 0, 0);
    }
}

// Original-orientation matmul (kept for the V stage, whose transposed store
// wants rows-per-reg): acc[rt][c][r] = OUT[rt*16+quad*4+r][(ct0+c)*16+m]
__device__ __forceinline__ void mm_acc(const __hip_bfloat16* A,
                                       const __hip_bfloat16* __restrict__ wT,
                                       int m, int quad, int ct0, f32x4 acc[2][2])
{
    const f32x4 z = {0.f, 0.f, 0.f, 0.f};
    acc[0][0] = z; acc[0][1] = z; acc[1][0] = z; acc[1][1] = z;
#pragma unroll
    for (int kk = 0; kk < 128; kk += 32) {
        const int k = kk + quad * 8;
        bfrag a0 = *(const bfrag*)(A + m * LDK + k);
        bfrag a1 = *(const bfrag*)(A + (16 + m) * LDK + k);
        bfrag b0 = *(const bfrag*)(wT + (size_t)(ct0 * 16 + m) * 128 + k);
        bfrag b1 = *(const bfrag*)(wT + (size_t)((ct0 + 1) * 16 + m) * 128 + k);
        acc[0][0] = __builtin_amdgcn_mfma_f32_16x16x32_bf16(a0, b0, acc[0][0], 0, 0, 0);
        acc[1][0] = __builtin_amdgcn_mfma_f32_16x16x32_bf16(a1, b0, acc[1][0], 0, 0, 0);
        acc[0][1] = __builtin_amdgcn_mfma_f32_16x16x32_bf16(a0, b1, acc[0][1], 0, 0, 0);
        acc[1][1] = __builtin_amdgcn_mfma_f32_16x16x32_bf16(a1, b1, acc[1][1], 0, 0, 0);
    }
}

// vectorized 8B store of a swapped-orientation accumulator
__device__ __forceinline__ void store_t(__hip_bfloat16* dst, f32x4 acc[2][2],
                                        int m, int quad, int ct0)
{
#pragma unroll
    for (int rt = 0; rt < 2; ++rt)
#pragma unroll
        for (int c = 0; c < 2; ++c) {
            __hip_bfloat16 pk[4];
#pragma unroll
            for (int r = 0; r < 4; ++r) pk[r] = __float2bfloat16(acc[rt][c][r]);
            *(short4v*)(dst + (rt * 16 + m) * LDK + (ct0 + c) * 16 + quad * 4) =
                *(const short4v*)pk;
        }
}

// LayerNorm over 128 elems x 32 rows: 8 threads/row, 16 elems each. Vectorized.
__device__ __forceinline__ void ln_step(const __hip_bfloat16* in, __hip_bfloat16* outb,
                                        const float* __restrict__ g,
                                        const float* __restrict__ bb, int tid)
{
    int row = tid >> 3;
    int part = tid & 7;
    const __hip_bfloat16* p = in + row * LDK + part * 16;
    bfrag h0 = *(const bfrag*)p;
    bfrag h1 = *(const bfrag*)(p + 8);
    float x[16];
#pragma unroll
    for (int j = 0; j < 8; ++j) { x[j] = b2f(h0[j]); x[8 + j] = b2f(h1[j]); }
    float s = 0.f, s2 = 0.f;
#pragma unroll
    for (int j = 0; j < 16; ++j) { s += x[j]; s2 += x[j] * x[j]; }
#pragma unroll
    for (int off = 1; off < 8; off <<= 1) {
        s += __shfl_xor(s, off, 64);
        s2 += __shfl_xor(s2, off, 64);
    }
    float mu = s * (1.f / 128.f);
    float var = s2 * (1.f / 128.f) - mu * mu;
    float sc = rsqrtf(var + 1e-5f);
    __hip_bfloat16* o = outb + row * LDK + part * 16;
#pragma unroll
    for (int j4 = 0; j4 < 4; ++j4) {
        float4 g4 = *(const float4*)(g + part * 16 + j4 * 4);
        float4 b4 = *(const float4*)(bb + part * 16 + j4 * 4);
        float gg[4] = {g4.x, g4.y, g4.z, g4.w};
        float bbv[4] = {b4.x, b4.y, b4.z, b4.w};
        __hip_bfloat16 pk[4];
#pragma unroll
        for (int r = 0; r < 4; ++r)
            pk[r] = __float2bfloat16((x[j4 * 4 + r] - mu) * sc * gg[r] + bbv[r]);
        *(short4v*)(o + j4 * 4) = *(const short4v*)pk;
    }
}

__global__ __launch_bounds__(256) void fused_model(
    const float* __restrict__ agent_embed,   // [B,16,128]
    const float* __restrict__ city_embed,    // [B,128,128]
    const int* __restrict__ acts,            // [B,16]
    const __hip_bfloat16* __restrict__ wts,  // 8 x WT[128][128] bf16
    const float* __restrict__ ln1g, const float* __restrict__ ln1b,
    const float* __restrict__ b1, const float* __restrict__ b2,
    const float* __restrict__ ln2g, const float* __restrict__ ln2b,
    float* __restrict__ out)                 // [B,16,16]
{
    __shared__ __align__(16) __hip_bfloat16 sXA[32 * LDK];  // agent -> O -> Z
    __shared__ __align__(16) __hip_bfloat16 sXS[32 * LDK];  // selected -> CAC
    __shared__ __align__(16) __hip_bfloat16 sK [32 * LDK];  // K -> H -> QS
    __shared__ __align__(16) __hip_bfloat16 sV [32 * LDK];  // Vt[2][8][16][16] -> F1
    __shared__ __align__(16) __hip_bfloat16 sKS[32 * LDK];  // KS (live to end)
    __shared__ __align__(16) __hip_bfloat16 sQ [32 * LDK];  // Q -> Y
    __shared__ int sActs[32];

    const int tid = threadIdx.x;
    const int lane = tid & 63;
    const int wave = tid >> 6;
    const int m = lane & 15;
    const int quad = lane >> 4;
    const int ct0 = wave * 2;
    const int b0 = blockIdx.x * 2;

    // ---------------- stage A: acts, XA (agent), XS (gathered city)
    if (tid < 32) sActs[tid] = acts[b0 * 16 + tid];
    {
        const float4* src = (const float4*)(agent_embed + (size_t)b0 * 16 * 128);
#pragma unroll
        for (int p = 0; p < 4; ++p) {
            int v = p * 256 + tid;
            float4 f = src[v];
            int flat = v * 4;
            __hip_bfloat16 pk[4];
            pk[0] = __float2bfloat16(f.x); pk[1] = __float2bfloat16(f.y);
            pk[2] = __float2bfloat16(f.z); pk[3] = __float2bfloat16(f.w);
            *(short4v*)(sXA + (flat >> 7) * LDK + (flat & 127)) = *(const short4v*)pk;
        }
    }
    {
        int r = tid >> 3, part = tid & 7;
        int b = b0 + (r >> 4), i = r & 15;
        int act = acts[b * 16 + i];
        const float4* src = (const float4*)(city_embed + ((size_t)b * 128 + act) * 128);
        __hip_bfloat16* d = sXS + r * LDK + part * 16;
#pragma unroll
        for (int p = 0; p < 4; ++p) {
            float4 f = src[part * 4 + p];
            __hip_bfloat16 pk[4];
            pk[0] = __float2bfloat16(f.x); pk[1] = __float2bfloat16(f.y);
            pk[2] = __float2bfloat16(f.z); pk[3] = __float2bfloat16(f.w);
            *(short4v*)(d + p * 4) = *(const short4v*)pk;
        }
    }
    __syncthreads();

    f32x4 acc[2][2];

    // ---------------- S1: K = agent @ Wk
    mm_accT(sXA, wts + 1 * 16384, m, quad, ct0, acc); store_t(sK, acc, m, quad, ct0);
    // ---------------- S2: V = agent @ Wv, stored TRANSPOSED: Vt[g][h][d][k]
    mm_acc(sXA, wts + 2 * 16384, m, quad, ct0, acc);
#pragma unroll
    for (int rt = 0; rt < 2; ++rt)
#pragma unroll
        for (int c = 0; c < 2; ++c) {
            __hip_bfloat16 pk[4];
#pragma unroll
            for (int r = 0; r < 4; ++r) pk[r] = __float2bfloat16(acc[rt][c][r]);
            // Vt[g=rt][h=ct0+c][d=m][k=quad*4+r]
            *(short4v*)(sV + ((rt * 8 + ct0 + c) * 16 + m) * 16 + quad * 4) =
                *(const short4v*)pk;
        }
    // ---------------- S3: KS = agent @ Wk_s
    mm_accT(sXA, wts + 7 * 16384, m, quad, ct0, acc); store_t(sKS, acc, m, quad, ct0);
    // ---------------- S4: Q = selected @ Wq
    mm_accT(sXS, wts + 0 * 16384, m, quad, ct0, acc); store_t(sQ, acc, m, quad, ct0);
    __syncthreads();

    // ---------------- S5: masked 8-head attention, dh=16 -> 16x16x16 MFMA.
    // S^T = K·Q^T so each lane holds P[q=m][k=quad*4+r] IN REGISTERS, which is
    // exactly the A-fragment layout for the PV 16x16x16 MFMA. No K-padding,
    // no P round-trip through LDS, softmax sum = 3 adds + 2 shuffles.
    {
        const f32x4 z4 = {0.f, 0.f, 0.f, 0.f};
        const int g = wave >> 1;           // batch within block (const per wave)
        const int aq = sActs[g * 16 + m];  // acts[q], q = m
        bool keep[4];
#pragma unroll
        for (int r = 0; r < 4; ++r) {
            int k = quad * 4 + r;
            int ak = sActs[g * 16 + k];
            keep[r] = (aq == 0) ? (k == m) : (ak == aq);
        }
#pragma unroll
        for (int pp = 0; pp < 4; ++pp) {
            const int h = (wave & 1) * 4 + pp;
            short4v kf = *(const short4v*)(sK + (g * 16 + m) * LDK + h * 16 + quad * 4);
            short4v qf = *(const short4v*)(sQ + (g * 16 + m) * LDK + h * 16 + quad * 4);
            f32x4 sc = __builtin_amdgcn_mfma_f32_16x16x16bf16_1k(kf, qf, z4, 0, 0, 0);
            // sc[r] = S[q=m][k=quad*4+r] (pre-scale)
            float e[4], s = 0.f;
#pragma unroll
            for (int r = 0; r < 4; ++r) {
                // scores tiny (|s|<~1): softmax without max-sub is exact enough
                e[r] = keep[r] ? __expf(sc[r] * 0.25f) : 0.f;
                s += e[r];
            }
            s += __shfl_xor(s, 16, 64);
            s += __shfl_xor(s, 32, 64);
            float inv = __builtin_amdgcn_rcpf(s);
            __hip_bfloat16 pk[4];
#pragma unroll
            for (int r = 0; r < 4; ++r) pk[r] = __float2bfloat16(e[r] * inv);
            short4v pa = *(const short4v*)pk;  // A-frag: P[q=m][k=quad*4+r]
            // B-frag: V^T[d=m][k=quad*4+i]
            short4v vf = *(const short4v*)(sV + ((g * 8 + h) * 16 + m) * 16 + quad * 4);
            f32x4 o4 = __builtin_amdgcn_mfma_f32_16x16x16bf16_1k(pa, vf, z4, 0, 0, 0);
            // o4[r] = O[q=quad*4+r][d=m]
#pragma unroll
            for (int r = 0; r < 4; ++r)
                sXA[(g * 16 + quad * 4 + r) * LDK + h * 16 + m] =
                    __float2bfloat16(o4[r]);
        }
    }
    __syncthreads();

    // ---------------- S6: Y = O @ Wo + selected (into sQ)
    mm_accT(sXA, wts + 3 * 16384, m, quad, ct0, acc);
#pragma unroll
    for (int rt = 0; rt < 2; ++rt)
#pragma unroll
        for (int c = 0; c < 2; ++c) {
            const int off = (rt * 16 + m) * LDK + (ct0 + c) * 16 + quad * 4;
            short4v sv = *(const short4v*)(sXS + off);
            __hip_bfloat16 pk[4];
#pragma unroll
            for (int r = 0; r < 4; ++r)
                pk[r] = __float2bfloat16(acc[rt][c][r] + b2f(sv[r]));
            *(short4v*)(sQ + off) = *(const short4v*)pk;
        }
    __syncthreads();

    // ---------------- S7: LN1(Y) -> H (into sK)
    ln_step(sQ, sK, ln1g, ln1b, tid);
    __syncthreads();

    // ---------------- S8: F1 = relu(H @ W1 + b1) (into sV; Vt is dead)
    mm_accT(sK, wts + 4 * 16384, m, quad, ct0, acc);
#pragma unroll
    for (int rt = 0; rt < 2; ++rt)
#pragma unroll
        for (int c = 0; c < 2; ++c) {
            float4 bv = *(const float4*)(b1 + (ct0 + c) * 16 + quad * 4);
            float bb4[4] = {bv.x, bv.y, bv.z, bv.w};
            __hip_bfloat16 pk[4];
#pragma unroll
            for (int r = 0; r < 4; ++r)
                pk[r] = __float2bfloat16(fmaxf(acc[rt][c][r] + bb4[r], 0.f));
            *(short4v*)(sV + (rt * 16 + m) * LDK + (ct0 + c) * 16 + quad * 4) =
                *(const short4v*)pk;
        }
    __syncthreads();

    // ---------------- S9: Z = H + F1 @ W2 + b2 (into sXA)
    mm_accT(sV, wts + 5 * 16384, m, quad, ct0, acc);
#pragma unroll
    for (int rt = 0; rt < 2; ++rt)
#pragma unroll
        for (int c = 0; c < 2; ++c) {
            const int off = (rt * 16 + m) * LDK + (ct0 + c) * 16 + quad * 4;
            float4 bv = *(const float4*)(b2 + (ct0 + c) * 16 + quad * 4);
            float bb4[4] = {bv.x, bv.y, bv.z, bv.w};
            short4v hv = *(const short4v*)(sK + off);
            __hip_bfloat16 pk[4];
#pragma unroll
            for (int r = 0; r < 4; ++r)
                pk[r] = __float2bfloat16(acc[rt][c][r] + bb4[r] + b2f(hv[r]));
            *(short4v*)(sXA + off) = *(const short4v*)pk;
        }
    __syncthreads();

    // ---------------- S10: LN2(Z) -> CAC (into sXS)
    ln_step(sXA, sXS, ln2g, ln2b, tid);
    __syncthreads();

    // ---------------- S11: QS = CAC @ Wq_s (into sK)
    mm_accT(sXS, wts + 6 * 16384, m, quad, ct0, acc);
    store_t(sK, acc, m, quad, ct0);
    __syncthreads();

    // ---------------- S12: logits = clip*tanh(QS @ KS^T / sqrt(E)), mask, store
    if (wave < 2) {
        int g = wave;
        f32x4 la = {0.f, 0.f, 0.f, 0.f};
#pragma unroll
        for (int kk = 0; kk < 128; kk += 32) {
            int k = kk + quad * 8;
            bfrag a = *(const bfrag*)(sK + (g * 16 + m) * LDK + k);   // QS rows
            bfrag b = *(const bfrag*)(sKS + (g * 16 + m) * LDK + k);  // KS rows
            la = __builtin_amdgcn_mfma_f32_16x16x32_bf16(a, b, la, 0, 0, 0);
        }
        int b = b0 + g;
        int kcol = m;
        int ak = sActs[g * 16 + kcol];
#pragma unroll
        for (int r = 0; r < 4; ++r) {
            int q = quad * 4 + r;
            int aq = sActs[g * 16 + q];
            float v = la[r] * 0.0883883476483184f;  // 1/sqrt(128)
            v = 10.f * tanhf(v);
            bool conflict = (aq == 0) ? (q == kcol) : (aq == ak);
            out[((size_t)b * 16 + q) * 16 + kcol] = conflict ? v : -1e9f;
        }
    }
}

extern "C" void kernel_launch(void* const* d_in, const int* in_sizes, int n_in,
                              void* d_out, int out_size, void* d_ws, size_t ws_size,
                              hipStream_t stream)
{
    const float* agent = (const float*)d_in[0];
    const float* city  = (const float*)d_in[1];
    const int*   acts  = (const int*)d_in[2];
    const float* Wq  = (const float*)d_in[3];
    const float* Wk  = (const float*)d_in[4];
    const float* Wv  = (const float*)d_in[5];
    const float* Wo  = (const float*)d_in[6];
    const float* l1g = (const float*)d_in[7];
    const float* l1b = (const float*)d_in[8];
    const float* W1  = (const float*)d_in[9];
    const float* b1  = (const float*)d_in[10];
    const float* W2  = (const float*)d_in[11];
    const float* b2  = (const float*)d_in[12];
    const float* l2g = (const float*)d_in[13];
    const float* l2b = (const float*)d_in[14];
    const float* Wqs = (const float*)d_in[15];
    const float* Wks = (const float*)d_in[16];
    float* out = (float*)d_out;

    int B = in_sizes[2] / 16;  // acts is [B,16]
    __hip_bfloat16* wts = (__hip_bfloat16*)d_ws;  // 8*16384 bf16 = 256 KB

    prep_weights<<<64, 256, 0, stream>>>(Wq, Wk, Wv, Wo, W1, W2, Wqs, Wks, wts);
    fused_model<<<B / 2, 256, 0, stream>>>(agent, city, acts, wts, l1g, l1b,
                                           b1, b2, l2g, l2b, out);
}